// Round 4
// baseline (173.627 us; speedup 1.0000x reference)
//
#include <hip/hip_runtime.h>

#define NI 64
#define NJ 8192
#define NK 128
#define JB 8                       // j's per block (and per wave) in K3
#define LOG2E 1.44269504088896340736f

typedef float f32x4 __attribute__((ext_vector_type(4)));

// workspace float offsets
#define WS_M    0         // M[kp][k] = sum_c Wk[c][kp]*Wq[c][k]   (16384)
#define WS_WVT  16384     // WvT[kp][c] = Wv[c][kp]                (16384)
#define WS_D    32768     // d[k] = sum_c Wq[c][k]*bk[c]           (128)
#define WS_KQ   32896     // kq_scaled[j][k] = log2e*(d + M^T x3)  (NJ*NK)

// ---------------- K1: tiny precompute of M, WvT, d ----------------
__global__ __launch_bounds__(128) void precompute_kernel(
    const float* __restrict__ Wv, const float* __restrict__ Wq,
    const float* __restrict__ Wk, const float* __restrict__ bk,
    float* __restrict__ ws)
{
    const int b = blockIdx.x;    // kp
    const int k = threadIdx.x;   // k
    float macc = 0.f, dacc = 0.f;
    for (int c = 0; c < NK; ++c) {
        float wq = Wq[c*NK + k];          // coalesced
        macc += Wk[c*NK + b] * wq;        // Wk col: uniform per block
        if (b == 0) dacc += bk[c] * wq;
    }
    ws[WS_M + b*NK + k] = macc;
    ws[WS_WVT + b*NK + k] = Wv[k*NK + b];
    if (b == 0) ws[WS_D + k] = dacc;
}

// ---------------- K2: kq_scaled[j,k] = log2e * (d[k] + sum_kp x3[j,kp]*M[kp,k]) ----------------
__global__ __launch_bounds__(256) void kq_kernel(
    const float* __restrict__ x, const int* __restrict__ pIdx,
    const float* __restrict__ ws, float* __restrict__ kqout)
{
    const int tid = threadIdx.x;
    const int k2  = tid & 63;          // k-pair index
    const int wv  = tid >> 6;
    const int j0  = blockIdx.x * 16 + wv * 4;
    const int idx = *pIdx;
    const float* __restrict__ M  = ws + WS_M;
    const float* __restrict__ x3 = x + (size_t)idx * NJ * NK;

    const float* r0 = x3 + (size_t)(j0+0)*NK;
    const float* r1 = x3 + (size_t)(j0+1)*NK;
    const float* r2 = x3 + (size_t)(j0+2)*NK;
    const float* r3 = x3 + (size_t)(j0+3)*NK;

    float d0 = ws[WS_D + 2*k2], d1 = ws[WS_D + 2*k2 + 1];
    float2 acc[4];
#pragma unroll
    for (int jj = 0; jj < 4; ++jj) { acc[jj].x = d0; acc[jj].y = d1; }

#pragma unroll 2
    for (int kp = 0; kp < NK; kp += 4) {
        float4 x0 = *(const float4*)(r0 + kp);   // uniform per wave -> broadcast
        float4 x1 = *(const float4*)(r1 + kp);
        float4 x2 = *(const float4*)(r2 + kp);
        float4 x3v = *(const float4*)(r3 + kp);
        float2 m0 = *(const float2*)(M + (kp+0)*NK + 2*k2);  // coalesced
        float2 m1 = *(const float2*)(M + (kp+1)*NK + 2*k2);
        float2 m2 = *(const float2*)(M + (kp+2)*NK + 2*k2);
        float2 m3 = *(const float2*)(M + (kp+3)*NK + 2*k2);
        acc[0].x += x0.x*m0.x + x0.y*m1.x + x0.z*m2.x + x0.w*m3.x;
        acc[0].y += x0.x*m0.y + x0.y*m1.y + x0.z*m2.y + x0.w*m3.y;
        acc[1].x += x1.x*m0.x + x1.y*m1.x + x1.z*m2.x + x1.w*m3.x;
        acc[1].y += x1.x*m0.y + x1.y*m1.y + x1.z*m2.y + x1.w*m3.y;
        acc[2].x += x2.x*m0.x + x2.y*m1.x + x2.z*m2.x + x2.w*m3.x;
        acc[2].y += x2.x*m0.y + x2.y*m1.y + x2.z*m2.y + x2.w*m3.y;
        acc[3].x += x3v.x*m0.x + x3v.y*m1.x + x3v.z*m2.x + x3v.w*m3.x;
        acc[3].y += x3v.x*m0.y + x3v.y*m1.y + x3v.z*m2.y + x3v.w*m3.y;
    }
#pragma unroll
    for (int jj = 0; jj < 4; ++jj) {
        float2 o; o.x = acc[jj].x * LOG2E; o.y = acc[jj].y * LOG2E;
        *(float2*)(kqout + (size_t)(j0+jj)*NK + 2*k2) = o;
    }
}

// ---------------- K3: fused att + softmax(base2) + y + feat ----------------
// Block: 4 waves, 8 consecutive j. Wave w handles i in [16w,16w+16).
// Per row i a wave reads x[i, j0:j0+8, :] = 4KB contiguous (4x dwordx4/lane).
// Lane mapping within instr q: j = j0 + 2q + (lane>>5), k0 = (lane&31)*4.
__global__ __launch_bounds__(256, 4) void att_y_feat_kernel(
    const float* __restrict__ x, const float* __restrict__ ws,
    const float* __restrict__ bv, float* __restrict__ out)
{
    __shared__ float yacc_s[4][JB][NK];   // 16 KB
    __shared__ float y_s[JB][NK];         // 4 KB
    __shared__ float m_s[4][JB], s_s[4][JB];

    const int tid  = threadIdx.x;
    const int lane = tid & 63;
    const int w    = tid >> 6;
    const int h    = lane >> 5;
    const int lq   = lane & 31;
    const int k0   = lq * 4;
    const int j0   = blockIdx.x * JB;
    const size_t ISTEP = (size_t)NJ * NK;

    const float* __restrict__ kq = ws + WS_KQ;

    // kq fragments for this lane's 4 (q,h) slices
    f32x4 kqv[4];
#pragma unroll
    for (int q = 0; q < 4; ++q)
        kqv[q] = *(const f32x4*)(kq + (size_t)(j0 + 2*q + h)*NK + k0);

    // stream base: row 16w, this block's j0, lane's (h,k0) position
    const float* xb = x + (size_t)(w*16) * ISTEP + (size_t)j0 * NK
                        + (size_t)h * NK + k0;

    f32x4 buf[3][4];
    auto issue = [&](int i, int slot) {
#pragma unroll
        for (int q = 0; q < 4; ++q)
            buf[slot][q] = __builtin_nontemporal_load(
                (const f32x4*)(xb + (size_t)i * ISTEP + q * 256));
    };

    float m[4] = {-3.0e38f, -3.0e38f, -3.0e38f, -3.0e38f};
    float s[4] = {0.f, 0.f, 0.f, 0.f};
    f32x4 yacc[4] = {};

    auto process = [&](int slot) {
        float p[4];
#pragma unroll
        for (int q = 0; q < 4; ++q) {
            f32x4 b = buf[slot][q];
            p[q] = b[0]*kqv[q][0] + b[1]*kqv[q][1] + b[2]*kqv[q][2] + b[3]*kqv[q][3];
        }
#pragma unroll
        for (int q = 0; q < 4; ++q) {
            p[q] += __shfl_xor(p[q], 1);
            p[q] += __shfl_xor(p[q], 2);
            p[q] += __shfl_xor(p[q], 4);
            p[q] += __shfl_xor(p[q], 8);
            p[q] += __shfl_xor(p[q], 16);
        }
#pragma unroll
        for (int q = 0; q < 4; ++q) {
            float mn = fmaxf(m[q], p[q]);
            float sc = __builtin_amdgcn_exp2f(m[q] - mn);   // 1 if max unchanged
            float e  = __builtin_amdgcn_exp2f(p[q] - mn);
            s[q] = s[q] * sc + e;
            f32x4 b = buf[slot][q];
            yacc[q][0] = yacc[q][0]*sc + e*b[0];
            yacc[q][1] = yacc[q][1]*sc + e*b[1];
            yacc[q][2] = yacc[q][2]*sc + e*b[2];
            yacc[q][3] = yacc[q][3]*sc + e*b[3];
            m[q] = mn;
        }
    };

    issue(0, 0); issue(1, 1); issue(2, 2);
#pragma unroll
    for (int i = 0; i < 16; ++i) {
        process(i % 3);
        if (i + 3 < 16) issue(i + 3, i % 3);
    }

    // publish wave-partial state
#pragma unroll
    for (int q = 0; q < 4; ++q)
        *(f32x4*)&yacc_s[w][2*q + h][k0] = yacc[q];
    if (lq == 0) {
#pragma unroll
        for (int q = 0; q < 4; ++q) {
            m_s[w][2*q + h] = m[q];
            s_s[w][2*q + h] = s[q];
        }
    }
    __syncthreads();

    // merge 4 wave-partials -> normalized y in LDS
    const int jj = tid >> 5;            // 0..7
    const int c0 = (tid & 31) * 4;
    {
        float mM = fmaxf(fmaxf(m_s[0][jj], m_s[1][jj]),
                         fmaxf(m_s[2][jj], m_s[3][jj]));
        float coef[4];
        float denom = 0.f;
#pragma unroll
        for (int wv = 0; wv < 4; ++wv) {
            float c = __builtin_amdgcn_exp2f(m_s[wv][jj] - mM);
            coef[wv] = c;
            denom += c * s_s[wv][jj];
        }
        float inv = 1.f / denom;
        f32x4 yv = {};
#pragma unroll
        for (int wv = 0; wv < 4; ++wv) {
            f32x4 t = *(const f32x4*)&yacc_s[wv][jj][c0];
            yv[0] += coef[wv] * t[0]; yv[1] += coef[wv] * t[1];
            yv[2] += coef[wv] * t[2]; yv[3] += coef[wv] * t[3];
        }
        yv[0] *= inv; yv[1] *= inv; yv[2] *= inv; yv[3] *= inv;
        *(f32x4*)&y_s[jj][c0] = yv;
    }
    __syncthreads();

    // feat[j0+jj][c0..c0+3] = bv + sum_kp y[jj][kp] * WvT[kp][c]
    {
        const float* __restrict__ WvT = ws + WS_WVT;
        f32x4 acc = *(const f32x4*)(bv + c0);
#pragma unroll 4
        for (int kp = 0; kp < NK; ++kp) {
            float yk = y_s[jj][kp];                       // broadcast in group
            f32x4 wv4 = *(const f32x4*)(WvT + (size_t)kp * NK + c0);
            acc[0] += yk * wv4[0]; acc[1] += yk * wv4[1];
            acc[2] += yk * wv4[2]; acc[3] += yk * wv4[3];
        }
        *(f32x4*)(out + (size_t)(j0 + jj) * NK + c0) = acc;
    }
}

extern "C" void kernel_launch(void* const* d_in, const int* in_sizes, int n_in,
                              void* d_out, int out_size, void* d_ws, size_t ws_size,
                              hipStream_t stream) {
    const float* x  = (const float*)d_in[0];
    const float* Wv = (const float*)d_in[1];
    const float* bv = (const float*)d_in[2];
    const float* Wq = (const float*)d_in[3];
    const float* bq = (const float*)d_in[4];  (void)bq;  // cancels in softmax over agents
    const float* Wk = (const float*)d_in[5];
    const float* bk = (const float*)d_in[6];
    const int*  idx = (const int*)d_in[7];
    float* ws  = (float*)d_ws;
    float* out = (float*)d_out;

    precompute_kernel<<<NK, NK, 0, stream>>>(Wv, Wq, Wk, bk, ws);
    kq_kernel<<<NJ/16, 256, 0, stream>>>(x, idx, ws, ws + WS_KQ);
    att_y_feat_kernel<<<NJ/JB, 256, 0, stream>>>(x, ws, bv, out);
}

// Round 5
// 99.452 us; speedup vs baseline: 1.7458x; 1.7458x over previous
//
#include <hip/hip_runtime.h>

#define NI 64
#define NJ 8192
#define NK 128
#define LOG2E 1.44269504088896340736f

typedef float f32x4 __attribute__((ext_vector_type(4)));

// workspace float offsets
#define WS_M    0         // M[kp][k] = sum_c Wk[c][kp]*Wq[c][k]   (16384)
#define WS_WVT  16384     // WvT[kp][c] = Wv[c][kp]                (16384)
#define WS_D    32768     // d[k] = sum_c Wq[c][k]*bk[c]           (128)
#define WS_KQ   32896     // kq_scaled[j][k] = log2e*(d + M^T x3)  (NJ*NK)

// ---------------- K1: tiny precompute of M, WvT, d ----------------
__global__ __launch_bounds__(128) void precompute_kernel(
    const float* __restrict__ Wv, const float* __restrict__ Wq,
    const float* __restrict__ Wk, const float* __restrict__ bk,
    float* __restrict__ ws)
{
    const int b = blockIdx.x;    // kp
    const int k = threadIdx.x;   // k
    float macc = 0.f, dacc = 0.f;
    for (int c = 0; c < NK; ++c) {
        float wq = Wq[c*NK + k];          // coalesced
        macc += Wk[c*NK + b] * wq;        // Wk col: uniform per block
        if (b == 0) dacc += bk[c] * wq;
    }
    ws[WS_M + b*NK + k] = macc;
    ws[WS_WVT + b*NK + k] = Wv[k*NK + b];
    if (b == 0) ws[WS_D + k] = dacc;
}

// ---------------- K2: kq_scaled[j,k] = log2e * (d[k] + sum_kp x3[j,kp]*M[kp,k]) ----------------
__global__ __launch_bounds__(256) void kq_kernel(
    const float* __restrict__ x, const int* __restrict__ pIdx,
    const float* __restrict__ ws, float* __restrict__ kqout)
{
    const int tid = threadIdx.x;
    const int k2  = tid & 63;          // k-pair index
    const int wv  = tid >> 6;
    const int j0  = blockIdx.x * 16 + wv * 4;
    const int idx = *pIdx;
    const float* __restrict__ M  = ws + WS_M;
    const float* __restrict__ x3 = x + (size_t)idx * NJ * NK;

    const float* r0 = x3 + (size_t)(j0+0)*NK;
    const float* r1 = x3 + (size_t)(j0+1)*NK;
    const float* r2 = x3 + (size_t)(j0+2)*NK;
    const float* r3 = x3 + (size_t)(j0+3)*NK;

    float d0 = ws[WS_D + 2*k2], d1 = ws[WS_D + 2*k2 + 1];
    float2 acc[4];
#pragma unroll
    for (int jj = 0; jj < 4; ++jj) { acc[jj].x = d0; acc[jj].y = d1; }

#pragma unroll 2
    for (int kp = 0; kp < NK; kp += 4) {
        float4 x0 = *(const float4*)(r0 + kp);   // uniform per wave -> broadcast
        float4 x1 = *(const float4*)(r1 + kp);
        float4 x2 = *(const float4*)(r2 + kp);
        float4 x3v = *(const float4*)(r3 + kp);
        float2 m0 = *(const float2*)(M + (kp+0)*NK + 2*k2);  // coalesced
        float2 m1 = *(const float2*)(M + (kp+1)*NK + 2*k2);
        float2 m2 = *(const float2*)(M + (kp+2)*NK + 2*k2);
        float2 m3 = *(const float2*)(M + (kp+3)*NK + 2*k2);
        acc[0].x += x0.x*m0.x + x0.y*m1.x + x0.z*m2.x + x0.w*m3.x;
        acc[0].y += x0.x*m0.y + x0.y*m1.y + x0.z*m2.y + x0.w*m3.y;
        acc[1].x += x1.x*m0.x + x1.y*m1.x + x1.z*m2.x + x1.w*m3.x;
        acc[1].y += x1.x*m0.y + x1.y*m1.y + x1.z*m2.y + x1.w*m3.y;
        acc[2].x += x2.x*m0.x + x2.y*m1.x + x2.z*m2.x + x2.w*m3.x;
        acc[2].y += x2.x*m0.y + x2.y*m1.y + x2.z*m2.y + x2.w*m3.y;
        acc[3].x += x3v.x*m0.x + x3v.y*m1.x + x3v.z*m2.x + x3v.w*m3.x;
        acc[3].y += x3v.x*m0.y + x3v.y*m1.y + x3v.z*m2.y + x3v.w*m3.y;
    }
#pragma unroll
    for (int jj = 0; jj < 4; ++jj) {
        float2 o; o.x = acc[jj].x * LOG2E; o.y = acc[jj].y * LOG2E;
        *(float2*)(kqout + (size_t)(j0+jj)*NK + 2*k2) = o;
    }
}

// ---------------- K3: fused att + online softmax + y + feat ----------------
// Each wave owns 2 consecutive j's for ALL 64 i-rows. Lane -> (jj = lane>>5,
// k0 = (lane&31)*4). One dwordx4 per lane per i-row = 1 KB contiguous per
// wave-instruction. 8-deep rotating register buffer, issue-before-consume.
// No LDS / barriers in the main loop; softmax state is replicated within each
// 32-lane group so no merge is needed.
__global__ __launch_bounds__(256, 4) void att_y_feat_kernel(
    const float* __restrict__ x, const float* __restrict__ ws,
    const float* __restrict__ bv, float* __restrict__ out)
{
    __shared__ float y_s[8][NK];    // 4 KB

    const int tid  = threadIdx.x;
    const int lane = tid & 63;
    const int w    = tid >> 6;
    const int jj   = lane >> 5;
    const int lq   = lane & 31;
    const int k0   = lq * 4;
    const int j    = blockIdx.x * 8 + w * 2 + jj;
    const size_t ISTEP = (size_t)NJ * NK;

    const f32x4 kqv = *(const f32x4*)(ws + WS_KQ + (size_t)j * NK + k0);
    const float* xb = x + (size_t)j * NK + k0;

    float m = -3.0e38f, s = 0.f;
    f32x4 yacc = {0.f, 0.f, 0.f, 0.f};

    auto step = [&](f32x4 b) {
        float p = b[0]*kqv[0] + b[1]*kqv[1] + b[2]*kqv[2] + b[3]*kqv[3];
        p += __shfl_xor(p, 1);
        p += __shfl_xor(p, 2);
        p += __shfl_xor(p, 4);
        p += __shfl_xor(p, 8);
        p += __shfl_xor(p, 16);          // full dot over k, within 32-lane group
        float mn = fmaxf(m, p);
        float sc = __builtin_amdgcn_exp2f(m - mn);   // 1.0 when max unchanged
        float e  = __builtin_amdgcn_exp2f(p - mn);
        s = s * sc + e;
        yacc[0] = yacc[0]*sc + e*b[0];
        yacc[1] = yacc[1]*sc + e*b[1];
        yacc[2] = yacc[2]*sc + e*b[2];
        yacc[3] = yacc[3]*sc + e*b[3];
        m = mn;
    };

    f32x4 buf[8];
#pragma unroll
    for (int t = 0; t < 8; ++t)
        buf[t] = *(const f32x4*)(xb + (size_t)t * ISTEP);

    for (int ib = 0; ib < 7; ++ib) {     // NOT unrolled: one 8-stage body
#pragma unroll
        for (int t = 0; t < 8; ++t) {
            f32x4 b = buf[t];
            buf[t] = *(const f32x4*)(xb + (size_t)((ib + 1) * 8 + t) * ISTEP);
            step(b);                     // issue-before-consume: 8 loads in flight
        }
    }
#pragma unroll
    for (int t = 0; t < 8; ++t)
        step(buf[t]);                    // epilogue rows 56..63

    // y for this lane's 4 k's (state identical across the 32-lane group)
    float inv = 1.f / s;
    f32x4 yv = { yacc[0]*inv, yacc[1]*inv, yacc[2]*inv, yacc[3]*inv };
    *(f32x4*)&y_s[w*2 + jj][k0] = yv;
    __syncthreads();

    // feat[j0+fj][c0..c0+3] = bv + sum_kp y[fj][kp] * WvT[kp][c]
    const int fj = tid >> 5;             // 0..7
    const int c0 = (tid & 31) * 4;
    const float* __restrict__ WvT = ws + WS_WVT;
    f32x4 acc = *(const f32x4*)(bv + c0);
#pragma unroll 8
    for (int kp = 0; kp < NK; ++kp) {
        float yk = y_s[fj][kp];                          // LDS broadcast
        f32x4 wv4 = *(const f32x4*)(WvT + (size_t)kp * NK + c0);  // L2-hit
        acc[0] += yk * wv4[0]; acc[1] += yk * wv4[1];
        acc[2] += yk * wv4[2]; acc[3] += yk * wv4[3];
    }
    *(f32x4*)(out + (size_t)(blockIdx.x * 8 + fj) * NK + c0) = acc;
}

extern "C" void kernel_launch(void* const* d_in, const int* in_sizes, int n_in,
                              void* d_out, int out_size, void* d_ws, size_t ws_size,
                              hipStream_t stream) {
    const float* x  = (const float*)d_in[0];
    const float* Wv = (const float*)d_in[1];
    const float* bv = (const float*)d_in[2];
    const float* Wq = (const float*)d_in[3];
    const float* bq = (const float*)d_in[4];  (void)bq;  // cancels in softmax over agents
    const float* Wk = (const float*)d_in[5];
    const float* bk = (const float*)d_in[6];
    const int*  idx = (const int*)d_in[7];
    float* ws  = (float*)d_ws;
    float* out = (float*)d_out;

    precompute_kernel<<<NK, NK, 0, stream>>>(Wv, Wq, Wk, bk, ws);
    kq_kernel<<<NJ/16, 256, 0, stream>>>(x, idx, ws, ws + WS_KQ);
    att_y_feat_kernel<<<NJ/8, 256, 0, stream>>>(x, ws, bv, out);
}